// Round 8
// baseline (59.332 us; speedup 1.0000x reference)
//
#include <hip/hip_runtime.h>

#define C 32
#define H 192
#define W 192
#define HW (H*W)        // 36864
#define NPIX (HW*2)     // 73728
#define KK 7

// ---------------- K1: z[hw][o*2+n] = sum_c cw[o,c]*x[c][hw][n] ----------------
// 1152 blocks = 8 XCD chunks of 144 = (18 hwblk x 8 o-passes of 4).
// XCD n covers pixel rows [24n, 24n+24) -- matches k2's band.
__global__ __launch_bounds__(256) void k1_mix(
    const float* __restrict__ x, const float* __restrict__ cw, float* __restrict__ z)
{
    __shared__ float wl[128];                    // wl[c*4+oo] = cw[ob+oo][c]
    const int b   = blockIdx.x;
    const int xcd = b & 7, idx = b >> 3;         // bijective (1152%8==0)
    const int hwblk = xcd * 18 + (idx >> 3);     // 0..143
    const int ob    = (idx & 7) * 4;             // o-pass of 4 channels
    const int tid   = threadIdx.x;

    if (tid < 128) wl[tid] = cw[(ob + (tid & 3)) * C + (tid >> 2)];
    __syncthreads();

    const int hw = hwblk * 256 + tid;
    const float2* x2 = reinterpret_cast<const float2*>(x);
    float2 xv[C];
#pragma unroll
    for (int c = 0; c < C; ++c) xv[c] = x2[(size_t)c * HW + hw];

    float acc[4][2];
#pragma unroll
    for (int oo = 0; oo < 4; ++oo) { acc[oo][0] = 0.f; acc[oo][1] = 0.f; }

#pragma unroll
    for (int c = 0; c < C; ++c) {
        const float4 wt = *reinterpret_cast<const float4*>(&wl[c * 4]);  // uniform broadcast
        acc[0][0] += wt.x * xv[c].x;  acc[0][1] += wt.x * xv[c].y;
        acc[1][0] += wt.y * xv[c].x;  acc[1][1] += wt.y * xv[c].y;
        acc[2][0] += wt.z * xv[c].x;  acc[2][1] += wt.z * xv[c].y;
        acc[3][0] += wt.w * xv[c].x;  acc[3][1] += wt.w * xv[c].y;
    }

    float* zp = z + (size_t)hw * 64 + ob * 2;    // 8 contiguous floats
    *reinterpret_cast<float4*>(zp)     = make_float4(acc[0][0], acc[0][1], acc[1][0], acc[1][1]);
    *reinterpret_cast<float4*>(zp + 4) = make_float4(acc[2][0], acc[2][1], acc[3][0], acc[3][1]);
}

// ---------------- K2: px-in-lanes, all-vector loads, no broadcast chains ----------------
// Block = 256 thr (4 waves). Wave = 4 w-px x 2 h-rows x 64 ch.
// lane = px*? no: lane = og*4+px?  -> lane&3 = px, lane>>2 = og (16 ch-quads).
// z: shared-col float4 window zw[10] (static idx); weights: per-lane masked loads.
#define K2_BLOCKS 1152   // 96 h-pairs x 12 wq

template<bool HEDGE>
__device__ __forceinline__ void k2_body(const float* __restrict__ z, const float* __restrict__ w1,
                                        int h0, int w0, int px, int og, bool wedge, float acc[2][4])
{
#pragma unroll
    for (int s = 0; s < 8; ++s) {
        const int yy = h0 - 3 + s;
        if (HEDGE && (yy < 0 || yy >= H)) continue;   // uniform; interior: branchless

        // shared-col z window: cols w0-3 .. w0+6, lane reads its 4-ch slice
        float4 zw[10];
        if (!wedge) {
            const float* p = z + ((size_t)yy * W + (w0 - 3)) * 64 + og * 4;
#pragma unroll
            for (int k = 0; k < 10; ++k)
                zw[k] = *reinterpret_cast<const float4*>(p + (size_t)k * 64);
        } else {
            const float* p = z + (size_t)yy * (W * 64) + og * 4;
#pragma unroll
            for (int k = 0; k < 10; ++k) {
                const int cc  = w0 - 3 + k;                     // uniform
                const int ccl = cc < 0 ? 0 : (cc > W - 1 ? W - 1 : cc);
                const float4 v = *reinterpret_cast<const float4*>(p + (size_t)ccl * 64);
                zw[k] = (cc == ccl) ? v : make_float4(0.f, 0.f, 0.f, 0.f);
            }
        }

        // output rows r=0,1: input row yy is tap i = s - r
#pragma unroll
        for (int r = 0; r < 2; ++r) {
            const int i = s - r;
            if (i < 0 || i > 6) continue;                       // compile-time
            const float* wrow = w1 + (size_t)i * KK * HW + (size_t)(h0 + r) * W + w0 + px;
#pragma unroll
            for (int k = 0; k < 10; ++k) {
                const int jj = k - px;                          // tap col for this lane
                const bool v = (jj >= 0) && (jj <= 6);
                const int jc = v ? jj : 0;                      // clamped, in-bounds
                const float wt = v ? wrow[(size_t)jc * HW] : 0.f;
                acc[r][0] += wt * zw[k].x;
                acc[r][1] += wt * zw[k].y;
                acc[r][2] += wt * zw[k].z;
                acc[r][3] += wt * zw[k].w;
            }
        }
    }
}

__global__ __launch_bounds__(256) void k2_conv(
    const float* __restrict__ z, const float* __restrict__ w1,
    const float* __restrict__ cb, float* __restrict__ out)
{
    const int b   = blockIdx.x;
    const int xcd = b & 7, idx = b >> 3;         // bijective XCD swizzle
    const int l   = xcd * (K2_BLOCKS / 8) + idx; // XCD n: h rows [24n, 24n+24)
    const int hp  = l / 12;                      // h-pair 0..95
    const int wq  = l % 12;
    const int h0  = hp * 2;
    const int tid  = threadIdx.x;
    const int wv   = __builtin_amdgcn_readfirstlane(tid >> 6);
    const int lane = tid & 63;
    const int px   = lane & 3;
    const int og   = lane >> 2;                  // ch-quad 0..15
    const int w0   = wq * 16 + wv * 4;           // wave's 4-px base

    float acc[2][4];
#pragma unroll
    for (int r = 0; r < 2; ++r)
#pragma unroll
        for (int e = 0; e < 4; ++e) acc[r][e] = 0.f;

    const bool wedge = (w0 == 0) || (w0 == W - 4);   // uniform
    if (h0 >= 3 && h0 <= H - 6) k2_body<false>(z, w1, h0, w0, px, og, wedge, acc);
    else                        k2_body<true >(z, w1, h0, w0, px, og, wedge, acc);

    // epilogue: lane holds ch og*4..+4 for (h0+r, w0+px); ch=o*2+n -> 2 o x 2 n
    const float b0 = cb[og * 2];
    const float b1 = cb[og * 2 + 1];
#pragma unroll
    for (int r = 0; r < 2; ++r) {
        const size_t pofs = ((size_t)(h0 + r) * W + w0 + px) * 2;
        float* p0 = out + (size_t)(og * 2)     * NPIX + pofs;
        float* p1 = out + (size_t)(og * 2 + 1) * NPIX + pofs;
        *reinterpret_cast<float2*>(p0) = make_float2(acc[r][0] + b0, acc[r][1] + b0);
        *reinterpret_cast<float2*>(p1) = make_float2(acc[r][2] + b1, acc[r][3] + b1);
    }
}

extern "C" void kernel_launch(void* const* d_in, const int* in_sizes, int n_in,
                              void* d_out, int out_size, void* d_ws, size_t ws_size,
                              hipStream_t stream) {
    const float* x  = (const float*)d_in[0];   // (C,H,W,2)
    const float* w1 = (const float*)d_in[1];   // (1,1,49,H,W)
    const float* cw = (const float*)d_in[2];   // (C_out, C_in)
    const float* cb = (const float*)d_in[3];   // (C,)
    float* z   = (float*)d_ws;                 // (HW, 64) transposed mix
    float* out = (float*)d_out;                // (C,H,W,2)

    hipLaunchKernelGGL(k1_mix, dim3(1152), dim3(256), 0, stream, x, cw, z);
    hipLaunchKernelGGL(k2_conv, dim3(K2_BLOCKS), dim3(256), 0, stream, z, w1, cb, out);
}

// Round 9
// 34.782 us; speedup vs baseline: 1.7058x; 1.7058x over previous
//
#include <hip/hip_runtime.h>

#define C 32
#define H 192
#define W 192
#define HW (H*W)        // 36864
#define NPIX (HW*2)     // 73728
#define KK 7
#define WP 200          // padded z row stride (cols), logical col c -> physical c+3
#define HPAD 198        // padded z rows, logical row y -> physical y+3
#define ZSZ ((size_t)HPAD * WP * 64)   // floats: 2,534,400 (~10.14 MB)

// ---------------- K1 (R7 structure): z[y][c][o*2+n] = sum_c' cw[o,c']*x[c'][y][c][n] ----------------
// Writes into the zero-padded z at physical ((y+3)*WP + (c+3))*64.
__global__ __launch_bounds__(256) void k1_mix(
    const float* __restrict__ x, const float* __restrict__ cw, float* __restrict__ z)
{
    __shared__ float wl[256];
    const int b  = blockIdx.x;
    const int l  = (b & 7) * 72 + (b >> 3);      // bijective XCD swizzle (576%8==0)
    const int hwblk = l >> 2;
    const int ob    = (l & 3) * 8;
    const int tid   = threadIdx.x;

    wl[tid] = cw[(ob + (tid & 7)) * C + (tid >> 3)];   // wl[c*8+oo]
    __syncthreads();

    const int hw = hwblk * 256 + tid;
    const float2* x2 = reinterpret_cast<const float2*>(x);
    float2 xv[C];
#pragma unroll
    for (int c = 0; c < C; ++c) xv[c] = x2[(size_t)c * HW + hw];

    float acc[8][2];
#pragma unroll
    for (int oo = 0; oo < 8; ++oo) { acc[oo][0] = 0.f; acc[oo][1] = 0.f; }

#pragma unroll
    for (int c = 0; c < C; ++c) {
        const float4 wa = *reinterpret_cast<const float4*>(&wl[c * 8]);
        const float4 wb = *reinterpret_cast<const float4*>(&wl[c * 8 + 4]);
        const float wt[8] = { wa.x, wa.y, wa.z, wa.w, wb.x, wb.y, wb.z, wb.w };
#pragma unroll
        for (int oo = 0; oo < 8; ++oo) {
            acc[oo][0] += wt[oo] * xv[c].x;
            acc[oo][1] += wt[oo] * xv[c].y;
        }
    }

    const int y = hw / W;
    const int c = hw - y * W;
    float* zp = z + ((size_t)(y + 3) * WP + (c + 3)) * 64 + ob * 2;
#pragma unroll
    for (int q = 0; q < 4; ++q) {
        float4 r = make_float4(acc[2*q][0], acc[2*q][1], acc[2*q+1][0], acc[2*q+1][1]);
        *reinterpret_cast<float4*>(zp + 4 * q) = r;
    }
}

// ---------------- K2: fully branchless over zero-padded z ----------------
// Block = 256 thr (4 waves); wave = 8 output px of row h, lane = o*2+n.
// Straight-line body: 98 coalesced z loads + 49 scalar weight loads + 392 FMAs,
// no edge branches anywhere -> loads pipeline freely across rows.
#define K2_BLOCKS 1152   // 192 rows x 6 wq
__global__ __launch_bounds__(256) void k2_conv(
    const float* __restrict__ z, const float* __restrict__ w1,
    const float* __restrict__ cb, float* __restrict__ out)
{
    __shared__ float tr[4][8 * 66];              // epilogue transpose only

    const int b  = blockIdx.x;
    const int l  = (b & 7) * (K2_BLOCKS / 8) + (b >> 3);  // XCD row bands (24 rows each)
    const int h  = l / 6;
    const int wq = l % 6;
    const int tid  = threadIdx.x;
    const int wv   = __builtin_amdgcn_readfirstlane(tid >> 6);  // uniform in SGPR
    const int lane = tid & 63;                   // o*2+n
    const int w0   = wq * 32 + wv * 8;

    float acc[8];
#pragma unroll
    for (int p = 0; p < 8; ++p) acc[p] = 0.f;

#pragma unroll
    for (int i = 0; i < KK; ++i) {
        // input logical row h+i-3 -> physical h+i; logical col w0-3 -> physical w0
        const float* p = z + ((size_t)(h + i) * WP + w0) * 64 + lane;
        float zw[14];
#pragma unroll
        for (int k = 0; k < 14; ++k) zw[k] = p[(size_t)k * 64];

        const float* wp = w1 + (size_t)i * KK * HW + (size_t)h * W + w0;  // uniform -> s_load
#pragma unroll
        for (int j = 0; j < KK; ++j) {
#pragma unroll
            for (int px = 0; px < 8; ++px)
                acc[px] += wp[(size_t)j * HW + px] * zw[j + px];
        }
    }

    // epilogue: bias + per-wave LDS transpose -> 16B stores (exact R7)
    const float bias = cb[lane >> 1];
    float* trw = &tr[wv][0];
#pragma unroll
    for (int p = 0; p < 8; ++p) trw[p * 66 + lane] = acc[p] + bias;
    __syncthreads();

    const int o = lane >> 1, half = lane & 1;
    float v8[8];
#pragma unroll
    for (int m = 0; m < 8; ++m) {
        const int f = half * 8 + m;
        v8[m] = trw[(f >> 1) * 66 + o * 2 + (f & 1)];
    }
    float* obase = out + (size_t)o * NPIX + ((size_t)h * W + w0) * 2 + half * 8;
    *reinterpret_cast<float4*>(obase)     = make_float4(v8[0], v8[1], v8[2], v8[3]);
    *reinterpret_cast<float4*>(obase + 4) = make_float4(v8[4], v8[5], v8[6], v8[7]);
}

extern "C" void kernel_launch(void* const* d_in, const int* in_sizes, int n_in,
                              void* d_out, int out_size, void* d_ws, size_t ws_size,
                              hipStream_t stream) {
    const float* x  = (const float*)d_in[0];   // (C,H,W,2)
    const float* w1 = (const float*)d_in[1];   // (1,1,49,H,W)
    const float* cw = (const float*)d_in[2];   // (C_out, C_in)
    const float* cb = (const float*)d_in[3];   // (C,)
    float* z   = (float*)d_ws;                 // padded (HPAD, WP, 64) transposed mix
    float* out = (float*)d_out;                // (C,H,W,2)

    // zero the padded z (halo must be 0; interior overwritten by k1)
    hipMemsetAsync(z, 0, ZSZ * sizeof(float), stream);
    hipLaunchKernelGGL(k1_mix, dim3(576), dim3(256), 0, stream, x, cw, z);
    hipLaunchKernelGGL(k2_conv, dim3(K2_BLOCKS), dim3(256), 0, stream, z, w1, cb, out);
}

// Round 10
// 26.800 us; speedup vs baseline: 2.2139x; 1.2978x over previous
//
#include <hip/hip_runtime.h>

#define C 32
#define H 192
#define W 192
#define HW (H*W)        // 36864
#define NPIX (HW*2)     // 73728
#define KK 7
#define WP 200          // padded z row stride (cols); logical col c -> physical c+3
#define HPAD 198        // padded z rows; logical row y -> physical y+3
#define ROW4 (WP*16)    // float4 per padded row = 3200

// ---------------- K1 + halo-zero fused ----------------
// Blocks 0..575: mix (R7/R9 structure). Blocks 576..619: zero the 684 KB halo.
__global__ __launch_bounds__(256) void k1_mix(
    const float* __restrict__ x, const float* __restrict__ cw, float* __restrict__ z)
{
    const int b   = blockIdx.x;
    const int tid = threadIdx.x;

    if (b >= 576) {                              // ---- halo-zero blocks ----
        const int b2 = b - 576;
        float4* z4 = reinterpret_cast<float4*>(z);
        const float4 zero4 = make_float4(0.f, 0.f, 0.f, 0.f);
        if (b2 < 20) {
            // top rows 0..2 / bottom rows 195..197: contiguous 9600-f4 chunks
            const int    chunk = b2 / 10;
            const int    cb2   = b2 % 10;
            const size_t base4 = chunk ? (size_t)195 * ROW4 : 0;
#pragma unroll
            for (int k = 0; k < 4; ++k) {
                const int idx4 = cb2 * 1024 + k * 256 + tid;
                if (idx4 < 3 * ROW4) z4[base4 + idx4] = zero4;
            }
        } else {
            // interior rows 3..194: left pad 48 f4 + right pad 80 f4 per row
            const int b3   = b2 - 20;            // 0..23
            const int f    = tid & 127;
            const int half = tid >> 7;
#pragma unroll
            for (int it = 0; it < 4; ++it) {
                const int    pr   = 3 + b3 * 8 + half + 2 * it;
                const size_t row4 = (size_t)pr * ROW4;
                const size_t o4   = (f < 48) ? (row4 + f) : (row4 + 3120 + (f - 48));
                z4[o4] = zero4;
            }
        }
        return;
    }

    // ---- mix blocks (exact R9) ----
    __shared__ float wl[256];
    const int l  = (b & 7) * 72 + (b >> 3);      // bijective XCD swizzle (576%8==0)
    const int hwblk = l >> 2;
    const int ob    = (l & 3) * 8;

    wl[tid] = cw[(ob + (tid & 7)) * C + (tid >> 3)];   // wl[c*8+oo]
    __syncthreads();

    const int hw = hwblk * 256 + tid;
    const float2* x2 = reinterpret_cast<const float2*>(x);
    float2 xv[C];
#pragma unroll
    for (int c = 0; c < C; ++c) xv[c] = x2[(size_t)c * HW + hw];

    float acc[8][2];
#pragma unroll
    for (int oo = 0; oo < 8; ++oo) { acc[oo][0] = 0.f; acc[oo][1] = 0.f; }

#pragma unroll
    for (int c = 0; c < C; ++c) {
        const float4 wa = *reinterpret_cast<const float4*>(&wl[c * 8]);
        const float4 wb = *reinterpret_cast<const float4*>(&wl[c * 8 + 4]);
        const float wt[8] = { wa.x, wa.y, wa.z, wa.w, wb.x, wb.y, wb.z, wb.w };
#pragma unroll
        for (int oo = 0; oo < 8; ++oo) {
            acc[oo][0] += wt[oo] * xv[c].x;
            acc[oo][1] += wt[oo] * xv[c].y;
        }
    }

    const int y = hw / W;
    const int c = hw - y * W;
    float* zp = z + ((size_t)(y + 3) * WP + (c + 3)) * 64 + ob * 2;
#pragma unroll
    for (int q = 0; q < 4; ++q) {
        float4 r = make_float4(acc[2*q][0], acc[2*q][1], acc[2*q+1][0], acc[2*q+1][1]);
        *reinterpret_cast<float4*>(zp + 4 * q) = r;
    }
}

// ---------------- K2: fully branchless over zero-padded z (byte-identical to R9) ----------------
#define K2_BLOCKS 1152   // 192 rows x 6 wq
__global__ __launch_bounds__(256) void k2_conv(
    const float* __restrict__ z, const float* __restrict__ w1,
    const float* __restrict__ cb, float* __restrict__ out)
{
    __shared__ float tr[4][8 * 66];              // epilogue transpose only

    const int b  = blockIdx.x;
    const int l  = (b & 7) * (K2_BLOCKS / 8) + (b >> 3);  // XCD row bands (24 rows each)
    const int h  = l / 6;
    const int wq = l % 6;
    const int tid  = threadIdx.x;
    const int wv   = __builtin_amdgcn_readfirstlane(tid >> 6);  // uniform in SGPR
    const int lane = tid & 63;                   // o*2+n
    const int w0   = wq * 32 + wv * 8;

    float acc[8];
#pragma unroll
    for (int p = 0; p < 8; ++p) acc[p] = 0.f;

#pragma unroll
    for (int i = 0; i < KK; ++i) {
        // input logical row h+i-3 -> physical h+i; logical col w0-3 -> physical w0
        const float* p = z + ((size_t)(h + i) * WP + w0) * 64 + lane;
        float zw[14];
#pragma unroll
        for (int k = 0; k < 14; ++k) zw[k] = p[(size_t)k * 64];

        const float* wp = w1 + (size_t)i * KK * HW + (size_t)h * W + w0;  // uniform -> s_load
#pragma unroll
        for (int j = 0; j < KK; ++j) {
#pragma unroll
            for (int px = 0; px < 8; ++px)
                acc[px] += wp[(size_t)j * HW + px] * zw[j + px];
        }
    }

    // epilogue: bias + per-wave LDS transpose -> 16B stores
    const float bias = cb[lane >> 1];
    float* trw = &tr[wv][0];
#pragma unroll
    for (int p = 0; p < 8; ++p) trw[p * 66 + lane] = acc[p] + bias;
    __syncthreads();

    const int o = lane >> 1, half = lane & 1;
    float v8[8];
#pragma unroll
    for (int m = 0; m < 8; ++m) {
        const int f = half * 8 + m;
        v8[m] = trw[(f >> 1) * 66 + o * 2 + (f & 1)];
    }
    float* obase = out + (size_t)o * NPIX + ((size_t)h * W + w0) * 2 + half * 8;
    *reinterpret_cast<float4*>(obase)     = make_float4(v8[0], v8[1], v8[2], v8[3]);
    *reinterpret_cast<float4*>(obase + 4) = make_float4(v8[4], v8[5], v8[6], v8[7]);
}

extern "C" void kernel_launch(void* const* d_in, const int* in_sizes, int n_in,
                              void* d_out, int out_size, void* d_ws, size_t ws_size,
                              hipStream_t stream) {
    const float* x  = (const float*)d_in[0];   // (C,H,W,2)
    const float* w1 = (const float*)d_in[1];   // (1,1,49,H,W)
    const float* cw = (const float*)d_in[2];   // (C_out, C_in)
    const float* cb = (const float*)d_in[3];   // (C,)
    float* z   = (float*)d_ws;                 // padded (HPAD, WP, 64) transposed mix
    float* out = (float*)d_out;                // (C,H,W,2)

    hipLaunchKernelGGL(k1_mix, dim3(576 + 44), dim3(256), 0, stream, x, cw, z);
    hipLaunchKernelGGL(k2_conv, dim3(K2_BLOCKS), dim3(256), 0, stream, z, w1, cb, out);
}